// Round 10
// baseline (281.135 us; speedup 1.0000x reference)
//
#include <hip/hip_runtime.h>
#include <hip/hip_bf16.h>
#include <cstddef>

// Problem constants
#define NPTS 4096
#define CCH  128
#define KNN  9
#define GRP  4
#define BB   4
// workspace layout (float offsets)
#define OFF_XT    0u          // 2097152 floats (reused as zpre after k_attn)
#define OFF_XX    2097152u    // 16384
#define OFF_XHI   2113536u    // 1048576 float-slots = 2097152 bf16 (pre-swizzled)
#define OFF_IDX   3162112u    // 147456 ints
#define OFF_O     3309568u    // 4849664 (candbuf aliases first 2097152 floats)
#define OFF_Y     8159232u    // 2097152
#define OFF_GNP   10256384u   // 131072
#define OFF_WP    10388480u   // 65536
#define OFF_BIASP 10454016u   // 512
#define OFF_BNSUM 10454528u   // 128
#define OFF_BNSQ  10454656u   // 128

using bf16x8 = __attribute__((ext_vector_type(8))) short;
using f32x4  = __attribute__((ext_vector_type(4))) float;

// compare-exchange, descending (a keeps max) — v_max_f32/v_min_f32, parallel ILP
#define CE(a, b) { float _h = fmaxf(a, b); b = fminf(a, b); a = _h; }

// Sentinel: packed(-FLT_MAX, idx=0) = 0xFF7FF000 — finite huge-negative float,
// always below any real packed key (|key| <= O(100)); never NaN.
#define SENT_BITS 0xFF7FF000u

// ---------------- K1: transpose [B,C,N] -> xt [B*N,C] fp32 + pre-swizzled bf16 xhi + xx ----
// xhi swizzle: 16B granule g (8 bf16) of row R stored at slot g ^ (R&15). k_knn reads
// logical granule (ks*4+quad) of row R at physical slot (ks*4+quad)^(R&15).
__global__ void k_transpose(const float* __restrict__ x, float* __restrict__ xt,
                            __hip_bfloat16* __restrict__ xhi, float* __restrict__ xx) {
  __shared__ float t[32][33];
  int tx = threadIdx.x, ty = threadIdx.y;
  int n0 = blockIdx.x * 32, c0 = blockIdx.y * 32, b = blockIdx.z;
  float v = x[((size_t)b * CCH + c0 + ty) * NPTS + n0 + tx];
  t[ty][tx] = v;
  __syncthreads();
  float tv = t[tx][ty];
  size_t R = (size_t)b * NPTS + n0 + ty;
  int c = c0 + tx;
  xt[R * CCH + c] = tv;
  int g = c >> 3, w = c & 7;
  int sc = (((g ^ ((n0 + ty) & 15)) << 3) | w);
  xhi[R * CCH + sc] = __float2bfloat16(tv);
  if (ty == 0) {
    float s = 0.f;
    #pragma unroll
    for (int k = 0; k < 32; k++) { float u = t[k][tx]; s += u * u; }
    atomicAdd(&xx[b * NPTS + n0 + tx], s);
  }
}

// ---------------- K2: LDS-free MFMA Gram (bf16) + per-chunk sort-network top-8 ---------
// R9 showed VALUBusy 47% at 2 blocks/CU: the per-chunk __syncthreads + vmcnt(0) DMA
// drain stalled ~50% of cycles. The 1 MB batch is L2-resident and each 16-B granule is
// consumed by exactly one lane (wave-private rows), so LDS staging had zero reuse value.
// Now: A-frags read directly from pre-swizzled global (full 64-B lines per 16-row group)
// with a register double-buffer prefetching chunk c+1 during chunk c — compiler emits
// fine-grained vmcnt(8) per use, no barriers at all.
static __device__ __forceinline__ void knn_chunk(
    int c, const uint4* __restrict__ buf, const float* __restrict__ xxb,
    int wave, int quad, const bf16x8 (*qfrag)[4], float (*top8)[8]) {
  // fold -xx/2 into the accumulator init (rank key = inner - xx/2, monotone in pd)
  f32x4 cinit[2];
  #pragma unroll
  for (int ct = 0; ct < 2; ct++)
    #pragma unroll
    for (int r = 0; r < 4; r++)
      cinit[ct][r] = -0.5f * xxb[c * 128 + wave * 32 + ct * 16 + quad * 4 + r];
  f32x4 acc[2][2];
  #pragma unroll
  for (int ct = 0; ct < 2; ct++)
    #pragma unroll
    for (int qt = 0; qt < 2; qt++) acc[ct][qt] = cinit[ct];
  #pragma unroll
  for (int ks = 0; ks < 4; ks++) {
    #pragma unroll
    for (int ct = 0; ct < 2; ct++) {
      bf16x8 af = __builtin_bit_cast(bf16x8, buf[ct * 4 + ks]);
      #pragma unroll
      for (int qt = 0; qt < 2; qt++)
        acc[ct][qt] = __builtin_amdgcn_mfma_f32_16x16x32_bf16(
            af, qfrag[qt][ks], acc[ct][qt], 0, 0, 0);
    }
  }
  // selection: pack idx into low 12 mantissa bits; Batcher sort-8 + bitonic keep-top-8
  const unsigned cbase = (unsigned)(c * 128 + wave * 32 + quad * 4);
  #pragma unroll
  for (int qt = 0; qt < 2; qt++) {
    float k[8];
    #pragma unroll
    for (int ct = 0; ct < 2; ct++)
      #pragma unroll
      for (int r = 0; r < 4; r++) {
        unsigned u = __float_as_uint(acc[ct][qt][r]);
        k[ct * 4 + r] = __uint_as_float((u & 0xFFFFF000u) |
                                        (cbase + (unsigned)(ct * 16 + r)));
      }
    // Batcher odd-even mergesort 8 (19 CE), descending
    CE(k[0],k[1]) CE(k[2],k[3]) CE(k[4],k[5]) CE(k[6],k[7])
    CE(k[0],k[2]) CE(k[1],k[3]) CE(k[4],k[6]) CE(k[5],k[7])
    CE(k[1],k[2]) CE(k[5],k[6])
    CE(k[0],k[4]) CE(k[1],k[5]) CE(k[2],k[6]) CE(k[3],k[7])
    CE(k[2],k[4]) CE(k[3],k[5])
    CE(k[1],k[2]) CE(k[3],k[4]) CE(k[5],k[6])
    // keep-top-8 of union: bitonic first stage + 12-CE re-sort
    float t[8];
    #pragma unroll
    for (int i = 0; i < 8; i++) t[i] = fmaxf(top8[qt][i], k[7 - i]);
    CE(t[0],t[4]) CE(t[1],t[5]) CE(t[2],t[6]) CE(t[3],t[7])
    CE(t[0],t[2]) CE(t[1],t[3]) CE(t[4],t[6]) CE(t[5],t[7])
    CE(t[0],t[1]) CE(t[2],t[3]) CE(t[4],t[5]) CE(t[6],t[7])
    #pragma unroll
    for (int i = 0; i < 8; i++) top8[qt][i] = t[i];
  }
}

__launch_bounds__(256, 2)
__global__ void k_knn(const short* __restrict__ xhi, const float* __restrict__ xx,
                      float* __restrict__ cand) {
  const int tid = threadIdx.x;
  const int wave = tid >> 6, lane = tid & 63;
  const int quad = lane >> 4, m = lane & 15;
  const int b = blockIdx.y;
  const int q0 = blockIdx.x * 32;
  const short* xb = xhi + (size_t)b * NPTS * CCH;
  const float* xxb = xx + (b << 12);

  // query B-frags (un-swizzle: granule ks*4+quad at slot ^(row&15), row&15==m)
  bf16x8 qfrag[2][4];
  #pragma unroll
  for (int qt = 0; qt < 2; qt++) {
    const short* qrow = xb + (size_t)(q0 + qt * 16 + m) * CCH;
    #pragma unroll
    for (int ks = 0; ks < 4; ks++) {
      int slot = (ks * 4 + quad) ^ m;
      qfrag[qt][ks] = *(const bf16x8*)(qrow + slot * 8);
    }
  }

  float top8[2][8];
  #pragma unroll
  for (int qt = 0; qt < 2; qt++)
    #pragma unroll
    for (int p = 0; p < 8; p++) top8[qt][p] = __uint_as_float(SENT_BITS);

  // per-lane A-frag addressing in the pre-swizzled layout
  const short* abase = xb + (size_t)(wave * 32 + m) * CCH;
  int goff[8];
  #pragma unroll
  for (int ct = 0; ct < 2; ct++)
    #pragma unroll
    for (int ks = 0; ks < 4; ks++)
      goff[ct * 4 + ks] = ct * 16 * CCH + (((ks * 4 + quad) ^ m) * 8);

#define KNN_LOAD(buf, cc) { \
    const short* _p = abase + (size_t)(cc) * (128 * CCH); \
    _Pragma("unroll") \
    for (int _i = 0; _i < 8; _i++) (buf)[_i] = *(const uint4*)(_p + goff[_i]); }

  uint4 bufA[8], bufB[8];
  KNN_LOAD(bufA, 0)
  #pragma unroll 1
  for (int t = 0; t < 16; t++) {
    KNN_LOAD(bufB, 2 * t + 1)
    knn_chunk(2 * t, bufA, xxb, wave, quad, qfrag, top8);
    if (t < 15) KNN_LOAD(bufA, 2 * t + 2)
    knn_chunk(2 * t + 1, bufB, xxb, wave, quad, qfrag, top8);
  }
#undef KNN_LOAD

  int slot = wave * 4 + quad;
  #pragma unroll
  for (int qt = 0; qt < 2; qt++) {
    int q = q0 + qt * 16 + m;
    float* dst = cand + ((size_t)((b << 12) + q) * 16 + slot) * 8;
    #pragma unroll
    for (int p = 0; p < 8; p++) dst[p] = top8[qt][p];
  }
}

// ---------------- K2b: merge 128 packed -> top-16 -> exact fp32 re-rank -> top-9 --------
__launch_bounds__(256)
__global__ void k_rerank(const float* __restrict__ cand, const float* __restrict__ xt,
                         const float* __restrict__ xx, int* __restrict__ idxOut) {
  __shared__ __align__(16) float arr[4][128];
  __shared__ int selS[4][16];
  __shared__ float keyS[4][16];
  int tid = threadIdx.x, wave = tid >> 6, lane = tid & 63;
  int qg = blockIdx.x * 4 + wave;
  int b = qg >> 12;
  const float* src = cand + (size_t)qg * 128;
  float e1 = src[lane], e2 = src[lane + 64];
  arr[wave][lane] = e1; arr[wave][lane + 64] = e2;
  __syncthreads();
  int r1 = 0, r2 = 0;
  #pragma unroll 8
  for (int f = 0; f < 128; f += 4) {
    float4 fv = *(const float4*)&arr[wave][f];
    r1 += (fv.x > e1) + (fv.y > e1) + (fv.z > e1) + (fv.w > e1);
    r2 += (fv.x > e2) + (fv.y > e2) + (fv.z > e2) + (fv.w > e2);
  }
  if (r1 < 16) selS[wave][r1] = (int)(__float_as_uint(e1) & 0xFFFu);
  if (r2 < 16) selS[wave][r2] = (int)(__float_as_uint(e2) & 0xFFFu);
  __syncthreads();
  int cnum = lane >> 2, part = lane & 3;
  int cidx = selS[wave][cnum];
  const float* rq = xt + (size_t)qg * CCH;
  const float* rc = xt + ((size_t)(b << 12) + cidx) * CCH;
  float dot = 0.f;
  #pragma unroll
  for (int j = 0; j < 8; j++) {
    float4 a4 = *(const float4*)&rq[part * 32 + j * 4];
    float4 c4 = *(const float4*)&rc[part * 32 + j * 4];
    dot += a4.x * c4.x + a4.y * c4.y + a4.z * c4.z + a4.w * c4.w;
  }
  dot += __shfl_xor(dot, 1);
  dot += __shfl_xor(dot, 2);
  if (part == 0)
    keyS[wave][cnum] = fmaf(2.f, dot, -xx[(b << 12) + cidx]);
  __syncthreads();
  if (lane < 16) {
    float k = keyS[wave][lane]; int i = selS[wave][lane];
    int r = 0;
    #pragma unroll
    for (int f = 0; f < 16; f++) {
      float fk = keyS[wave][f]; int fi = selS[wave][f];
      r += (fk > k) || (fk == k && fi < i);
    }
    if (r < 9) idxOut[(size_t)qg * 9 + r] = i;
  }
}

// ---------------- K3: O[pos][0:128]=u=(Wa+Wb)x+b_lin, [128:256]=v=Wb x, [256:292]=aw ----
__launch_bounds__(256)
__global__ void k_linear(const float* __restrict__ xt, const float* __restrict__ w_lin,
                         const float* __restrict__ b_lin, const float* __restrict__ w_aw,
                         const float* __restrict__ b_aw, float* __restrict__ O) {
  __shared__ __align__(16) float Xs[64 * 132];
  __shared__ __align__(16) float Ws[64 * 132];
  int tid = threadIdx.x;
  int tx = tid & 15, ty = tid >> 4;
  int p0 = blockIdx.x * 64, o0 = blockIdx.y * 64;
  #pragma unroll
  for (int i = 0; i < 8; i++) {
    int flat = tid + i * 256; int r = flat >> 5, c4 = flat & 31;
    *(float4*)&Xs[r * 132 + c4 * 4] = *(const float4*)&xt[(size_t)(p0 + r) * CCH + c4 * 4];
  }
  #pragma unroll
  for (int i = 0; i < 8; i++) {
    int flat = tid + i * 256; int r = flat >> 5, c4 = flat & 31;
    int o = o0 + r; float4 v;
    if (o < 128) {
      float4 a = *(const float4*)&w_lin[(size_t)o * 256 + c4 * 4];
      float4 c = *(const float4*)&w_lin[(size_t)o * 256 + 128 + c4 * 4];
      v = make_float4(a.x + c.x, a.y + c.y, a.z + c.z, a.w + c.w);
    } else if (o < 256) {
      v = *(const float4*)&w_lin[(size_t)(o - 128) * 256 + 128 + c4 * 4];
    } else if (o < 292) {
      v = *(const float4*)&w_aw[(size_t)(o - 256) * 128 + c4 * 4];
    } else v = make_float4(0.f, 0.f, 0.f, 0.f);
    *(float4*)&Ws[r * 132 + c4 * 4] = v;
  }
  __syncthreads();
  float acc[4][4] = {};
  #pragma unroll 2
  for (int kq = 0; kq < 32; kq++) {
    float4 xa[4], wb[4];
    #pragma unroll
    for (int i = 0; i < 4; i++) xa[i] = *(const float4*)&Xs[(ty * 4 + i) * 132 + kq * 4];
    #pragma unroll
    for (int j = 0; j < 4; j++) wb[j] = *(const float4*)&Ws[(tx + 16 * j) * 132 + kq * 4];
    #pragma unroll
    for (int i = 0; i < 4; i++)
      #pragma unroll
      for (int j = 0; j < 4; j++)
        acc[i][j] += xa[i].x * wb[j].x + xa[i].y * wb[j].y + xa[i].z * wb[j].z + xa[i].w * wb[j].w;
  }
  #pragma unroll
  for (int j = 0; j < 4; j++) {
    int o = o0 + tx + 16 * j;
    if (o < 292) {
      float bias = (o < 128) ? b_lin[o] : ((o < 256) ? 0.f : b_aw[o - 256]);
      #pragma unroll
      for (int i = 0; i < 4; i++)
        O[(size_t)(p0 + ty * 4 + i) * 296 + o] = acc[i][j] + bias;
    }
  }
}

// ---------------- K4: per-point grouped attention, residual, GN partials ----------------
__launch_bounds__(256)
__global__ void k_attn(const float* __restrict__ O, const int* __restrict__ idxArr,
                       const float* __restrict__ xt, float* __restrict__ Y,
                       float* __restrict__ gnPart) {
  __shared__ __align__(16) float fF[4][1188];
  __shared__ __align__(16) float scS[4][432];
  __shared__ float awS[4][48];
  __shared__ float w9S[4][48];
  __shared__ int tI[45], tJ[45];
  int tid = threadIdx.x;
  int wave = tid >> 6, l = tid & 63;
  int pos = blockIdx.x * 4 + wave;
  int b = pos >> 12;
  if (tid == 0) {
    int p = 0;
    for (int i = 0; i < 9; i++) for (int j = i; j < 9; j++) { tI[p] = i; tJ[p] = j; p++; }
  }
  int nbr[9];
  const float* Op = O + (size_t)pos * 296;
  #pragma unroll
  for (int k = 0; k < 9; k++) nbr[k] = idxArr[(size_t)pos * 9 + k];
  float2 u = *(const float2*)(Op + 2 * l);
  float* fFw = fF[wave];
  #pragma unroll
  for (int k = 0; k < 9; k++) {
    const float* vp = O + (size_t)((b << 12) + nbr[k]) * 296 + 128;
    float2 vv = *(const float2*)(vp + 2 * l);
    *(float2*)&fFw[k * 132 + 2 * l] = make_float2(u.x - vv.x, u.y - vv.y);
  }
  __syncthreads();
  #pragma unroll
  for (int r = 0; r < 3; r++) {
    int p = r * 64 + l;
    if (p < 180) {
      int g = p / 45, q = p - g * 45;
      int i = tI[q], j = tJ[q];
      const float* fi = fFw + i * 132 + g * 32;
      const float* fj = fFw + j * 132 + g * 32;
      float s = 0.f;
      #pragma unroll
      for (int t8 = 0; t8 < 8; t8++) {
        float4 a4 = *(const float4*)(fi + 4 * t8);
        float4 b4 = *(const float4*)(fj + 4 * t8);
        s += a4.x * b4.x + a4.y * b4.y + a4.z * b4.z + a4.w * b4.w;
      }
      s *= 0.17677669529663687f; // 1/sqrt(32)
      scS[wave][(g * 9 + i) * 12 + j] = s;
      scS[wave][(g * 9 + j) * 12 + i] = s;
    }
  }
  __syncthreads();
  if (l < 36) {
    int g = l / 9, i = l - g * 9;
    float* rp = &scS[wave][(g * 9 + i) * 12];
    float mx = rp[0];
    #pragma unroll
    for (int j = 1; j < 9; j++) mx = fmaxf(mx, rp[j]);
    float e[9]; float sm = 0.f;
    #pragma unroll
    for (int j = 0; j < 9; j++) { e[j] = __expf(rp[j] - mx); sm += e[j]; }
    float inv = 1.f / sm;
    #pragma unroll
    for (int j = 0; j < 9; j++) rp[j] = e[j] * inv;
  } else if (l < 40) {
    int g = l - 36;
    float a[9]; float mx = -3.4e38f;
    #pragma unroll
    for (int k = 0; k < 9; k++) { a[k] = Op[256 + g * 9 + k]; mx = fmaxf(mx, a[k]); }
    float sm = 0.f;
    #pragma unroll
    for (int k = 0; k < 9; k++) { a[k] = __expf(a[k] - mx); sm += a[k]; }
    float inv = 1.f / sm;
    #pragma unroll
    for (int k = 0; k < 9; k++) awS[wave][g * 12 + k] = a[k] * inv;
  }
  __syncthreads();
  if (l < 36) {
    int g = l / 9, j = l - g * 9;
    float s = 0.f;
    #pragma unroll
    for (int i = 0; i < 9; i++) s += awS[wave][g * 12 + i] * scS[wave][(g * 9 + i) * 12 + j];
    w9S[wave][g * 12 + j] = s;
  }
  __syncthreads();
  int g = l >> 4;
  float w9r[9];
  #pragma unroll
  for (int j = 0; j < 9; j++) w9r[j] = w9S[wave][g * 12 + j];
  int c0 = 2 * l;
  float lf0 = 0.f, lf1 = 0.f;
  #pragma unroll
  for (int j = 0; j < 9; j++) {
    float2 f2 = *(const float2*)&fFw[j * 132 + c0];
    float e0 = f2.x > 0.f ? f2.x : __expf(f2.x) - 1.f;
    float e1 = f2.y > 0.f ? f2.y : __expf(f2.y) - 1.f;
    lf0 += w9r[j] * e0;
    lf1 += w9r[j] * e1;
  }
  float2 xv = *(const float2*)(xt + (size_t)pos * CCH + c0);
  float y0 = lf0 + xv.x, y1 = lf1 + xv.y;
  *(float2*)(Y + (size_t)pos * CCH + c0) = make_float2(y0, y1);
  float s1 = y0 + y1, s2 = y0 * y0 + y1 * y1;
  #pragma unroll
  for (int mm = 1; mm <= 8; mm <<= 1) { s1 += __shfl_xor(s1, mm); s2 += __shfl_xor(s2, mm); }
  if ((l & 15) == 0) {
    gnPart[(size_t)pos * 8 + g * 2]     = s1;
    gnPart[(size_t)pos * 8 + g * 2 + 1] = s2;
  }
}

// ---------------- K5: fused GN stats + fold into conv weights (one kernel per batch) ----
__global__ void k_gnfold(const float* __restrict__ gnPart,
                         const float* __restrict__ gn_g, const float* __restrict__ gn_b,
                         const float* __restrict__ conv_w, const float* __restrict__ conv_b,
                         float* __restrict__ Wp, float* __restrict__ biasp) {
  int b = blockIdx.x; int tid = threadIdx.x;
  int wave = tid >> 6, lane = tid & 63;
  __shared__ float aS[128], dS[128];
  {
    int g = wave; // one wave per group
    float s1 = 0.f, s2 = 0.f;
    for (int r = lane; r < NPTS; r += 64) {
      float2 p = *(const float2*)&gnPart[(size_t)(b * NPTS + r) * 8 + g * 2];
      s1 += p.x; s2 += p.y;
    }
    #pragma unroll
    for (int off = 1; off < 64; off <<= 1) { s1 += __shfl_xor(s1, off); s2 += __shfl_xor(s2, off); }
    float mu = s1 * (1.f / 131072.f);
    float var = s2 * (1.f / 131072.f) - mu * mu;
    float rs = 1.f / sqrtf(var + 1e-5f);
    if (lane < 32) {
      int c = g * 32 + lane;
      float a = rs * gn_g[c];
      aS[c] = a;
      dS[c] = gn_b[c] - mu * a;
    }
  }
  __syncthreads();
  for (int f = tid; f < 16384; f += 256)
    Wp[(size_t)b * 16384 + f] = conv_w[f] * aS[f & 127];
  if (tid < 128) {
    float s = conv_b[tid];
    for (int c = 0; c < 128; c++) s += conv_w[tid * 128 + c] * dS[c];
    biasp[b * 128 + tid] = s;
  }
}

// ---------------- K6: conv GEMM on raw y + BN partial sums ----------------
__launch_bounds__(256)
__global__ void k_conv(const float* __restrict__ Y, const float* __restrict__ Wp,
                       const float* __restrict__ biasp, float* __restrict__ zpre,
                       float* __restrict__ bnSum, float* __restrict__ bnSq) {
  __shared__ __align__(16) float Ys[64 * 132];
  __shared__ __align__(16) float Ws[64 * 132];
  int tid = threadIdx.x;
  int tx = tid & 15, ty = tid >> 4;
  int n0 = blockIdx.x * 64, o0 = blockIdx.y * 64, b = blockIdx.z;
  #pragma unroll
  for (int i = 0; i < 8; i++) {
    int flat = tid + i * 256; int r = flat >> 5, c4 = flat & 31;
    *(float4*)&Ys[r * 132 + c4 * 4] = *(const float4*)&Y[(size_t)((b << 12) + n0 + r) * CCH + c4 * 4];
    *(float4*)&Ws[r * 132 + c4 * 4] = *(const float4*)&Wp[(size_t)b * 16384 + (size_t)(o0 + r) * 128 + c4 * 4];
  }
  __syncthreads();
  float acc[4][4] = {};
  #pragma unroll 2
  for (int kq = 0; kq < 32; kq++) {
    float4 wa[4], yb[4];
    #pragma unroll
    for (int i = 0; i < 4; i++) wa[i] = *(const float4*)&Ws[(ty * 4 + i) * 132 + kq * 4];
    #pragma unroll
    for (int j = 0; j < 4; j++) yb[j] = *(const float4*)&Ys[(tx + 16 * j) * 132 + kq * 4];
    #pragma unroll
    for (int i = 0; i < 4; i++)
      #pragma unroll
      for (int j = 0; j < 4; j++)
        acc[i][j] += wa[i].x * yb[j].x + wa[i].y * yb[j].y + wa[i].z * yb[j].z + wa[i].w * yb[j].w;
  }
  #pragma unroll
  for (int i = 0; i < 4; i++) {
    int o = o0 + ty * 4 + i;
    float bias = biasp[b * 128 + o];
    float p1 = 0.f, p2 = 0.f;
    #pragma unroll
    for (int j = 0; j < 4; j++) {
      float z = acc[i][j] + bias;
      zpre[(((size_t)((b << 7) + o)) << 12) + n0 + tx + 16 * j] = z;
      p1 += z; p2 += z * z;
    }
    #pragma unroll
    for (int mm = 1; mm <= 8; mm <<= 1) { p1 += __shfl_xor(p1, mm); p2 += __shfl_xor(p2, mm); }
    if (tx == 0) { atomicAdd(&bnSum[o], p1); atomicAdd(&bnSq[o], p2); }
  }
}

// ---------------- K7: BN finalize (inline) + normalize + ReLU -> d_out ----------------
// Block covers 1024 consecutive elements => o is block-uniform; bnSum/bnSq reads broadcast.
__global__ void k_final(const float* __restrict__ zpre, const float* __restrict__ bnSum,
                        const float* __restrict__ bnSq, const float* __restrict__ bn_g,
                        const float* __restrict__ bn_b, float* __restrict__ out) {
  int i4 = blockIdx.x * 256 + threadIdx.x;
  int e = i4 * 4;
  int o = (e >> 12) & 127;
  float m = bnSum[o] * (1.f / 16384.f);
  float v = bnSq[o] * (1.f / 16384.f) - m * m;
  float sc = bn_g[o] / sqrtf(v + 1e-5f);
  float sh = bn_b[o] - m * sc;
  float4 z = *(const float4*)&zpre[e];
  float4 r;
  r.x = fmaxf(fmaf(z.x, sc, sh), 0.f);
  r.y = fmaxf(fmaf(z.y, sc, sh), 0.f);
  r.z = fmaxf(fmaf(z.z, sc, sh), 0.f);
  r.w = fmaxf(fmaf(z.w, sc, sh), 0.f);
  *(float4*)&out[e] = r;
}

extern "C" void kernel_launch(void* const* d_in, const int* in_sizes, int n_in,
                              void* d_out, int out_size, void* d_ws, size_t ws_size,
                              hipStream_t stream) {
  const float* features = (const float*)d_in[0];
  const float* w_lin  = (const float*)d_in[1];
  const float* b_lin  = (const float*)d_in[2];
  const float* w_aw   = (const float*)d_in[3];
  const float* b_aw   = (const float*)d_in[4];
  const float* gn_g   = (const float*)d_in[5];
  const float* gn_b   = (const float*)d_in[6];
  const float* conv_w = (const float*)d_in[7];
  const float* conv_b = (const float*)d_in[8];
  const float* bn_g   = (const float*)d_in[9];
  const float* bn_b   = (const float*)d_in[10];

  float* ws    = (float*)d_ws;
  float* xt    = ws + OFF_XT;
  float* xxp   = ws + OFF_XX;
  __hip_bfloat16* xhip = (__hip_bfloat16*)(ws + OFF_XHI);
  int*   idxp  = (int*)(ws + OFF_IDX);
  float* Op    = ws + OFF_O;
  float* candp = ws + OFF_O;   // alias: dead before k_linear writes O
  float* Yp    = ws + OFF_Y;
  float* gnp   = ws + OFF_GNP;
  float* Wp    = ws + OFF_WP;
  float* biasp = ws + OFF_BIASP;
  float* bnSum = ws + OFF_BNSUM;
  float* bnSq  = ws + OFF_BNSQ;
  float* zpre  = xt; // alias: xt dead after k_attn

  hipMemsetAsync(xxp, 0, NPTS * BB * sizeof(float), stream);
  hipMemsetAsync(bnSum, 0, 256 * sizeof(float), stream); // bnSum + bnSq contiguous

  k_transpose<<<dim3(128, 4, 4), dim3(32, 32), 0, stream>>>(features, xt, xhip, xxp);
  k_knn<<<dim3(128, 4), 256, 0, stream>>>((const short*)xhip, xxp, candp);
  k_rerank<<<4096, 256, 0, stream>>>(candp, xt, xxp, idxp);
  k_linear<<<dim3(256, 5), 256, 0, stream>>>(xt, w_lin, b_lin, w_aw, b_aw, Op);
  k_attn<<<4096, 256, 0, stream>>>(Op, idxp, xt, Yp, gnp);
  k_gnfold<<<4, 256, 0, stream>>>(gnp, gn_g, gn_b, conv_w, conv_b, Wp, biasp);
  k_conv<<<dim3(64, 2, 4), 256, 0, stream>>>(Yp, Wp, biasp, zpre, bnSum, bnSq);
  k_final<<<2048, 256, 0, stream>>>(zpre, bnSum, bnSq, bn_g, bn_b, (float*)d_out);
}